// Round 1
// 1966.942 us; speedup vs baseline: 3.1543x; 3.1543x over previous
//
#include <hip/hip_runtime.h>
#include <hip/hip_bf16.h>

using u16 = unsigned short;

#define BB 2
#define TT 2048
#define DD 256
#define HH_ 4
#define KK 1024
#define NN 4096
#define VV 32000
#define BT 4096
#define LL 6

typedef __attribute__((ext_vector_type(8))) short short8;
typedef __attribute__((ext_vector_type(4))) float f32x4;

__device__ __forceinline__ float b2f(u16 u) {
    union { unsigned int i; float f; } cv; cv.i = ((unsigned int)u) << 16; return cv.f;
}
__device__ __forceinline__ u16 f2b(float f) {
    union { float f; unsigned int i; } cv; cv.f = f;
    const unsigned int u = cv.i;
    return (u16)((u + 0x7fffu + ((u >> 16) & 1u)) >> 16);   // RNE
}
__device__ __forceinline__ float rdF(const float* p) { return *p; }
__device__ __forceinline__ float rdF(const u16* p)   { return b2f(*p); }
__device__ __forceinline__ void stF(float* p, float v) { *p = v; }
__device__ __forceinline__ void stF(u16* p, float v)   { *p = f2b(v); }

// ---------------- block-wide sum over 256 threads (4 waves) ----------------
__device__ __forceinline__ float block_sum_256(float val, float* sbuf) {
#pragma unroll
    for (int off = 32; off > 0; off >>= 1)
        val += __shfl_down(val, off, 64);
    const int lane = threadIdx.x & 63;
    const int wid  = threadIdx.x >> 6;
    __syncthreads();
    if (lane == 0) sbuf[wid] = val;
    __syncthreads();
    return sbuf[0] + sbuf[1] + sbuf[2] + sbuf[3];
}

// ---------------- rope tables (fp64 for angle accuracy) ----------------
__global__ void k_sincos(float* __restrict__ cosT, float* __restrict__ sinT) {
    const int t = blockIdx.x;
    for (int k = threadIdx.x; k < KK; k += blockDim.x) {
        const int f = k & 511;
        const double invf = exp(-((double)(2 * f) / (double)KK) * 9.210340371976184);
        const double th = (double)t * invf;
        double s, c;
        sincos(th, &s, &c);
        cosT[t * KK + k] = (float)c;
        sinT[t * KK + k] = (float)s;
    }
}

// ---------------- v = ln(emb[input_]) ----------------
__global__ void k_embed_ln(const int* __restrict__ idx, const float* __restrict__ emb,
                           float* __restrict__ v) {
    __shared__ float sbuf[4];
    const int r = blockIdx.x;
    const int token = idx[r];
    const float xv = emb[(long)token * DD + threadIdx.x];
    const float mu = block_sum_256(xv, sbuf) * (1.f / DD);
    const float d = xv - mu;
    const float var = block_sum_256(d * d, sbuf) * (1.f / DD);
    v[(long)r * DD + threadIdx.x] = d / sqrtf(var + 1e-5f);
}

// ---------------- ln rows of a (fp32) -> lnab (bf16) ----------------
__global__ void k_ln_rows_out(const float* __restrict__ a, u16* __restrict__ o) {
    __shared__ float sbuf[4];
    const long r = blockIdx.x;
    const float xv = a[r * DD + threadIdx.x];
    const float mu = block_sum_256(xv, sbuf) * (1.f / DD);
    const float d = xv - mu;
    const float var = block_sum_256(d * d, sbuf) * (1.f / DD);
    o[r * DD + threadIdx.x] = f2b(d / sqrtf(var + 1e-5f));
}

// ---------------- v = ln(v + ln(zb)); also emit vbf ----------------
__global__ void k_fin_ln(float* __restrict__ v, const float* __restrict__ z,
                         u16* __restrict__ vbf) {
    __shared__ float sbuf[4];
    const long r = blockIdx.x;
    const float zv = z[r * DD + threadIdx.x];
    const float mu1 = block_sum_256(zv, sbuf) * (1.f / DD);
    const float d1 = zv - mu1;
    const float var1 = block_sum_256(d1 * d1, sbuf) * (1.f / DD);
    const float lnz = d1 / sqrtf(var1 + 1e-5f);
    const float u = v[r * DD + threadIdx.x] + lnz;
    const float mu2 = block_sum_256(u, sbuf) * (1.f / DD);
    const float d2 = u - mu2;
    const float var2 = block_sum_256(d2 * d2, sbuf) * (1.f / DD);
    const float res = d2 / sqrtf(var2 + 1e-5f);
    v[r * DD + threadIdx.x] = res;
    vbf[r * DD + threadIdx.x] = f2b(res);
}

// ---------------- v += pos; emit vbf ----------------
__global__ void k_addpos(float* __restrict__ v, const float* __restrict__ pos,
                         u16* __restrict__ vbf) {
    const int i = blockIdx.x * 256 + threadIdx.x;
    const int d = i & (DD - 1);
    const int r = i >> 8;
    const int t = r & (TT - 1);
    const float nv = v[i] + pos[t * DD + d];
    v[i] = nv;
    vbf[i] = f2b(nv);
}

// ---------------- transpose+convert: in [z][R][C] -> out bf16 [z][C][R] ----------------
template <typename TIN>
__global__ __launch_bounds__(256)
void k_trans(const TIN* __restrict__ in, u16* __restrict__ out, int R, int C) {
    __shared__ float tile[32][33];
    const long zo = (long)blockIdx.z * (long)R * (long)C;
    const int r0 = blockIdx.y * 32, c0 = blockIdx.x * 32;
    const int tx = threadIdx.x & 31, ty = threadIdx.x >> 5;
#pragma unroll
    for (int u = 0; u < 32; u += 8)
        tile[ty + u][tx] = rdF(&in[zo + (long)(r0 + ty + u) * C + c0 + tx]);
    __syncthreads();
#pragma unroll
    for (int u = 0; u < 32; u += 8)
        out[zo + (long)(c0 + ty + u) * R + r0 + tx] = f2b(tile[tx][ty + u]);
}

// ---------------- rope: x(bf16) -> q(bf16) and qT(bf16) ----------------
// block: 64 t-rows x 64 k-cols (low half) + paired high half (k+512)
__global__ __launch_bounds__(256)
void k_rope_t(const u16* __restrict__ x, const float* __restrict__ cosT,
              const float* __restrict__ sinT, u16* __restrict__ q, u16* __restrict__ qT) {
    __shared__ u16 Sa[64][72];
    __shared__ u16 Sb[64][72];
    const long zoff = (long)blockIdx.z * TT * KK;
    const int t0 = blockIdx.y * 64;
    const int klo = blockIdx.x * 64;
    const int khi = klo + 512;
    const int tx = threadIdx.x & 63;
    const int ty = threadIdx.x >> 6;
#pragma unroll
    for (int u = 0; u < 64; u += 4) {
        const int t = t0 + u + ty;
        const long rb = (long)t * KK;
        const float xa = b2f(x[zoff + rb + klo + tx]);
        const float xb = b2f(x[zoff + rb + khi + tx]);
        const float ca = cosT[rb + klo + tx];
        const float sa = sinT[rb + klo + tx];
        const float cb = cosT[rb + khi + tx];
        const float sb = sinT[rb + khi + tx];
        const float qa = xa * ca - xb * sa;   // k <  512: rotate_half = -x[k+512]
        const float qb = xb * cb + xa * sb;   // k >= 512: rotate_half =  x[k-512]
        const u16 qab = f2b(qa), qbb = f2b(qb);
        q[zoff + rb + klo + tx] = qab;
        q[zoff + rb + khi + tx] = qbb;
        Sa[u + ty][tx] = qab;
        Sb[u + ty][tx] = qbb;
    }
    __syncthreads();
#pragma unroll
    for (int u = 0; u < 64; u += 4) {
        const int r = u + ty;
        qT[zoff + (long)(klo + r) * TT + t0 + tx] = Sa[tx][r];
        qT[zoff + (long)(khi + r) * TT + t0 + tx] = Sb[tx][r];
    }
}

// ---------------- bf16 MFMA GEMM ----------------
// C[m,n] = epi( sum_k A[m,k] * Bt[n,k] )   A:[M,Kin] bf16, Bt:[N,Kin] bf16
// 128x128 tile, BK=64, 4 waves (2x2), each wave 64x64 via 4x4 frags of 16x16x32.
// LDS XOR slot-swizzle: phys16Bslot = logical ^ (row & 7)  (write & read sides).
// EPI: 0=none 1=relu 2=relu*G.  batch z: zo=z/HH, zi=z%HH strides.
template <int EPI, typename TC>
__global__ __launch_bounds__(256)
void gemm_mfma(const u16* __restrict__ Ab, const u16* __restrict__ Btb,
               TC* __restrict__ Cb, const u16* __restrict__ Gb,
               int M, int N, int Kin, int lda, int ldb, int ldc, int ldg,
               long sAo, long sAi, long sBo, long sBi,
               long sCo, long sCi, long sGo, long sGi, int HH)
{
    const int z = blockIdx.z;
    const int zo = z / HH, zi = z - zo * HH;
    const u16* A  = Ab  + zo * sAo + zi * sAi;
    const u16* Bt = Btb + zo * sBo + zi * sBi;
    TC* C = Cb + zo * sCo + zi * sCi;
    const u16* G = (EPI == 2) ? (Gb + zo * sGo + zi * sGi) : nullptr;

    const int m0 = blockIdx.y * 128;
    const int n0 = blockIdx.x * 128;
    const int tid = threadIdx.x;
    const int lane = tid & 63;
    const int wv = tid >> 6;
    const int wr = (wv >> 1) * 64;
    const int wc = (wv & 1) * 64;

    __shared__ u16 As[128 * 64];
    __shared__ u16 Bs[128 * 64];

    f32x4 acc[4][4];
    const f32x4 vzero = {0.f, 0.f, 0.f, 0.f};
#pragma unroll
    for (int i = 0; i < 4; ++i)
#pragma unroll
        for (int j = 0; j < 4; ++j) acc[i][j] = vzero;

    const int srow  = tid >> 3;               // 0..31
    const int slotL = tid & 7;
    const int slotP = slotL ^ (srow & 7);
    const u16* Arow = A  + (long)(m0 + srow) * lda + slotL * 8;
    const u16* Brow = Bt + (long)(n0 + srow) * ldb + slotL * 8;

    const int rl = lane & 15;
    const int kg = lane >> 4;

    for (int k0 = 0; k0 < Kin; k0 += 64) {
#pragma unroll
        for (int it = 0; it < 4; ++it) {
            const int r = it * 32 + srow;
            short8 av = *(const short8*)(Arow + (long)it * 32 * lda + k0);
            short8 bv = *(const short8*)(Brow + (long)it * 32 * ldb + k0);
            *(short8*)(&As[r * 64 + slotP * 8]) = av;
            *(short8*)(&Bs[r * 64 + slotP * 8]) = bv;
        }
        __syncthreads();
#pragma unroll
        for (int kk = 0; kk < 2; ++kk) {
            short8 af[4], bfr[4];
            const int sl = kk * 4 + kg;
#pragma unroll
            for (int i = 0; i < 4; ++i) {
                const int row = wr + i * 16 + rl;
                af[i] = *(const short8*)(&As[row * 64 + (sl ^ (row & 7)) * 8]);
            }
#pragma unroll
            for (int j = 0; j < 4; ++j) {
                const int col = wc + j * 16 + rl;
                bfr[j] = *(const short8*)(&Bs[col * 64 + (sl ^ (col & 7)) * 8]);
            }
#pragma unroll
            for (int i = 0; i < 4; ++i)
#pragma unroll
                for (int j = 0; j < 4; ++j)
                    acc[i][j] = __builtin_amdgcn_mfma_f32_16x16x32_bf16(af[i], bfr[j], acc[i][j], 0, 0, 0);
        }
        __syncthreads();
    }

    // C/D layout: col = lane&15, row = (lane>>4)*4 + reg  [m89-verified]
#pragma unroll
    for (int i = 0; i < 4; ++i) {
#pragma unroll
        for (int rr = 0; rr < 4; ++rr) {
            const int m = m0 + wr + i * 16 + kg * 4 + rr;
#pragma unroll
            for (int j = 0; j < 4; ++j) {
                const int n = n0 + wc + j * 16 + rl;
                float val = acc[i][j][rr];
                if (EPI >= 1) val = fmaxf(val, 0.f);
                if (EPI == 2) val *= b2f(G[(long)m * ldg + n]);
                stF(&C[(long)m * ldc + n], val);
            }
        }
    }
}

extern "C" void kernel_launch(void* const* d_in, const int* in_sizes, int n_in,
                              void* d_out, int out_size, void* d_ws, size_t ws_size,
                              hipStream_t stream)
{
    const int* input_ = (const int*)d_in[0];
    const float* emb = (const float*)d_in[1];
    const float* pos = (const float*)d_in[2];
    const float* Dx = (const float*)d_in[3];
    const float* Dy = (const float*)d_in[4];
    const float* E  = (const float*)d_in[5];
    const float* readout = (const float*)d_in[6];
    float* out = (float*)d_out;

    // -------- workspace layout (byte offsets); total ~157.7 MiB --------
    char* base = (char*)d_ws;
    const long MiB = 1024 * 1024;
    float* v    = (float*)(base + 0);        //  4 MiB  fp32 residual stream
    float* zb   = (float*)(base + 4  * MiB); //  4 MiB  fp32
    float* cosT = (float*)(base + 8  * MiB); //  8 MiB
    float* sinT = (float*)(base + 16 * MiB); //  8 MiB
    u16* vbf  = (u16*)(base + 24 * MiB);     //  2 MiB  bf16 [B][T][D]
    u16* vbfT = (u16*)(base + 26 * MiB);     //  2 MiB  bf16 [B][D][T]
    u16* wT   = (u16*)(base + 28 * MiB);     //  4 MiB  bf16 [B][H][D][K]
    u16* x    = (u16*)(base + 32 * MiB);     // 32 MiB  bf16 [B][H][T][K]
    u16* q    = (u16*)(base + 64 * MiB);     // 32 MiB  bf16 [B][H][T][K]
    u16* y    = q;                           // 16 MiB alias: q dead after a-gemm
    u16* qT   = (u16*)(base + 96 * MiB);     // 32 MiB  bf16 [B][H][K][T]
    float* a  = (float*)qT;                  // 16 MiB alias: qT dead after wT-gemm
    u16* lnab = (u16*)(base + 128 * MiB);    //  8 MiB  bf16 [B][H][T][D]
    u16* DxT  = (u16*)(base + 136 * MiB);    //  2 MiB  bf16 [H][K][D]
    u16* DyT  = (u16*)(base + 138 * MiB);    //  2 MiB  bf16 [H][K][D]
    u16* ET   = (u16*)(base + 140 * MiB);    //  2 MiB  bf16 [D][NN]
    u16* roT  = (u16*)(base + 142 * MiB);    // 15.63 MiB bf16 [V][D]

    // -------- constants: transpose+convert once per call --------
    k_trans<float><<<dim3(KK / 32, DD / 32, HH_), 256, 0, stream>>>(Dx, DxT, DD, KK);
    k_trans<float><<<dim3(KK / 32, DD / 32, HH_), 256, 0, stream>>>(Dy, DyT, DD, KK);
    k_trans<float><<<dim3(DD / 32, NN / 32, 1),   256, 0, stream>>>(E, ET, NN, DD);
    k_trans<float><<<dim3(VV / 32, DD / 32, 1),   256, 0, stream>>>(readout, roT, DD, VV);
    k_sincos<<<TT, 256, 0, stream>>>(cosT, sinT);
    k_embed_ln<<<BT, 256, 0, stream>>>(input_, emb, v);

    for (int l = 0; l < LL; ++l) {
        k_addpos<<<BT, 256, 0, stream>>>(v, pos, vbf);
        k_trans<u16><<<dim3(DD / 32, TT / 32, BB), 256, 0, stream>>>(vbf, vbfT, TT, DD);

        // x[b,h] = relu(v[b] @ Dx[h]) : M=T, N=K, Kin=D
        gemm_mfma<1, u16><<<dim3(KK / 128, TT / 128, BB * HH_), 256, 0, stream>>>(
            vbf, DxT, x, nullptr,
            TT, KK, DD, DD, DD, KK, 0,
            (long)TT * DD, 0, 0, (long)KK * DD,
            (long)HH_ * TT * KK, (long)TT * KK, 0, 0, HH_);

        k_rope_t<<<dim3(8, TT / 64, BB * HH_), 256, 0, stream>>>(x, cosT, sinT, q, qT);

        // wT[b,h] = v[b]^T @ q[b,h]  (scores associativity) : M=D, N=K, Kin=T
        gemm_mfma<0, u16><<<dim3(KK / 128, DD / 128, BB * HH_), 256, 0, stream>>>(
            vbfT, qT, wT, nullptr,
            DD, KK, TT, TT, TT, KK, 0,
            (long)DD * TT, 0, (long)HH_ * KK * TT, (long)KK * TT,
            (long)HH_ * DD * KK, (long)DD * KK, 0, 0, HH_);

        // a[b,h] = q[b,h] @ w[b,h] : M=T, N=D, Kin=K  (fp32 out for LN)
        gemm_mfma<0, float><<<dim3(DD / 128, TT / 128, BB * HH_), 256, 0, stream>>>(
            q, wT, a, nullptr,
            TT, DD, KK, KK, KK, DD, 0,
            (long)HH_ * TT * KK, (long)TT * KK, (long)HH_ * DD * KK, (long)DD * KK,
            (long)HH_ * TT * DD, (long)TT * DD, 0, 0, HH_);

        k_ln_rows_out<<<BB * HH_ * TT, 256, 0, stream>>>(a, lnab);

        // y[b,t,h*K+k] = relu(ln_a @ Dy[h]) * x : M=T, N=K, Kin=D (y aliases q)
        gemm_mfma<2, u16><<<dim3(KK / 128, TT / 128, BB * HH_), 256, 0, stream>>>(
            lnab, DyT, y, x,
            TT, KK, DD, DD, DD, NN, KK,
            (long)HH_ * TT * DD, (long)TT * DD, 0, (long)KK * DD,
            (long)TT * NN, (long)KK, (long)HH_ * TT * KK, (long)TT * KK, HH_);

        // zb = y @ E : M=BT, N=D, Kin=NN  (fp32 out)
        gemm_mfma<0, float><<<dim3(DD / 128, BT / 128, 1), 256, 0, stream>>>(
            y, ET, zb, nullptr,
            BT, DD, NN, NN, NN, DD, 0,
            0, 0, 0, 0, 0, 0, 0, 0, 1);

        k_fin_ln<<<BT, 256, 0, stream>>>(v, zb, vbf);
    }

    // out = v @ readout : M=BT, N=V, Kin=D (fp32 out)
    gemm_mfma<0, float><<<dim3(VV / 128, BT / 128, 1), 256, 0, stream>>>(
        vbf, roT, out, nullptr,
        BT, VV, DD, DD, DD, VV, 0,
        0, 0, 0, 0, 0, 0, 0, 0, 1);
}

// Round 2
// 1746.397 us; speedup vs baseline: 3.5527x; 1.1263x over previous
//
#include <hip/hip_runtime.h>
#include <hip/hip_bf16.h>

using u16 = unsigned short;

#define BB 2
#define TT 2048
#define DD 256
#define HH_ 4
#define KK 1024
#define NN 4096
#define VV 32000
#define BT 4096
#define LL 6

typedef __attribute__((ext_vector_type(8))) short short8;
typedef __attribute__((ext_vector_type(4))) float f32x4;

__device__ __forceinline__ float b2f(u16 u) {
    union { unsigned int i; float f; } cv; cv.i = ((unsigned int)u) << 16; return cv.f;
}
__device__ __forceinline__ u16 f2b(float f) {
    union { float f; unsigned int i; } cv; cv.f = f;
    const unsigned int u = cv.i;
    return (u16)((u + 0x7fffu + ((u >> 16) & 1u)) >> 16);   // RNE
}
__device__ __forceinline__ float rdF(const float* p) { return *p; }
__device__ __forceinline__ float rdF(const u16* p)   { return b2f(*p); }
__device__ __forceinline__ void stF(float* p, float v) { *p = v; }
__device__ __forceinline__ void stF(u16* p, float v)   { *p = f2b(v); }

// ---------------- block-wide sum over 256 threads (4 waves) ----------------
__device__ __forceinline__ float block_sum_256(float val, float* sbuf) {
#pragma unroll
    for (int off = 32; off > 0; off >>= 1)
        val += __shfl_down(val, off, 64);
    const int lane = threadIdx.x & 63;
    const int wid  = threadIdx.x >> 6;
    __syncthreads();
    if (lane == 0) sbuf[wid] = val;
    __syncthreads();
    return sbuf[0] + sbuf[1] + sbuf[2] + sbuf[3];
}

// ---------------- rope tables, halved: cos/sin[t][f], f<512 ----------------
// emb = concat([freqs,freqs]) => table[k] == table[k-512] for k>=512.
__global__ void k_sincos(float* __restrict__ cosH, float* __restrict__ sinH) {
    const int t = blockIdx.x;
    for (int f = threadIdx.x; f < 512; f += blockDim.x) {
        const double invf = exp(-((double)(2 * f) / (double)KK) * 9.210340371976184); // ln(10000)
        const double th = (double)t * invf;
        double s, c;
        sincos(th, &s, &c);
        cosH[t * 512 + f] = (float)c;
        sinH[t * 512 + f] = (float)s;
    }
}

// ---------------- v = ln(emb[input_]) + pos (layer-0 pos fused) ----------------
__global__ void k_embed_ln(const int* __restrict__ idx, const float* __restrict__ emb,
                           const float* __restrict__ pos,
                           float* __restrict__ v, u16* __restrict__ vbf) {
    __shared__ float sbuf[4];
    const int r = blockIdx.x;
    const int t = r & (TT - 1);
    const int token = idx[r];
    const float xv = emb[(long)token * DD + threadIdx.x];
    const float mu = block_sum_256(xv, sbuf) * (1.f / DD);
    const float d = xv - mu;
    const float var = block_sum_256(d * d, sbuf) * (1.f / DD);
    const float res = d / sqrtf(var + 1e-5f) + pos[t * DD + threadIdx.x];
    v[(long)r * DD + threadIdx.x] = res;
    vbf[(long)r * DD + threadIdx.x] = f2b(res);
}

// ---------------- ln rows of a (fp32) -> lnab (bf16) ----------------
__global__ void k_ln_rows_out(const float* __restrict__ a, u16* __restrict__ o) {
    __shared__ float sbuf[4];
    const long r = blockIdx.x;
    const float xv = a[r * DD + threadIdx.x];
    const float mu = block_sum_256(xv, sbuf) * (1.f / DD);
    const float d = xv - mu;
    const float var = block_sum_256(d * d, sbuf) * (1.f / DD);
    o[r * DD + threadIdx.x] = f2b(d / sqrtf(var + 1e-5f));
}

// ---------------- v = ln(v + ln(sum zp)) (+pos for next layer); emit vbf ----------------
__global__ void k_fin_ln(float* __restrict__ v, const float* __restrict__ zp,
                         const float* __restrict__ pos, u16* __restrict__ vbf,
                         int addp) {
    __shared__ float sbuf[4];
    const long r = blockIdx.x;
    const int t = (int)(r & (TT - 1));
    const long i = r * DD + threadIdx.x;
    const long S = (long)BT * DD;
    const float zv = zp[i] + zp[i + S] + zp[i + 2 * S] + zp[i + 3 * S];
    const float mu1 = block_sum_256(zv, sbuf) * (1.f / DD);
    const float d1 = zv - mu1;
    const float var1 = block_sum_256(d1 * d1, sbuf) * (1.f / DD);
    const float lnz = d1 / sqrtf(var1 + 1e-5f);
    const float u = v[i] + lnz;
    const float mu2 = block_sum_256(u, sbuf) * (1.f / DD);
    const float d2 = u - mu2;
    const float var2 = block_sum_256(d2 * d2, sbuf) * (1.f / DD);
    float res = d2 / sqrtf(var2 + 1e-5f);
    if (addp) res += pos[t * DD + threadIdx.x];
    v[i] = res;
    vbf[i] = f2b(res);
}

// ---------------- transpose+convert: in [z][R][C] -> out bf16 [z][C][R] ----------------
template <typename TIN>
__global__ __launch_bounds__(256)
void k_trans(const TIN* __restrict__ in, u16* __restrict__ out, int R, int C) {
    __shared__ float tile[32][33];
    const long zo = (long)blockIdx.z * (long)R * (long)C;
    const int r0 = blockIdx.y * 32, c0 = blockIdx.x * 32;
    const int tx = threadIdx.x & 31, ty = threadIdx.x >> 5;
#pragma unroll
    for (int u = 0; u < 32; u += 8)
        tile[ty + u][tx] = rdF(&in[zo + (long)(r0 + ty + u) * C + c0 + tx]);
    __syncthreads();
#pragma unroll
    for (int u = 0; u < 32; u += 8)
        out[zo + (long)(c0 + ty + u) * R + r0 + tx] = f2b(tile[tx][ty + u]);
}

// ---------------- rope: x(bf16) -> q(bf16) and qT(bf16); halved tables ----------------
__global__ __launch_bounds__(256)
void k_rope_t(const u16* __restrict__ x, const float* __restrict__ cosH,
              const float* __restrict__ sinH, u16* __restrict__ q, u16* __restrict__ qT) {
    __shared__ u16 Sa[64][72];
    __shared__ u16 Sb[64][72];
    const long zoff = (long)blockIdx.z * TT * KK;
    const int t0 = blockIdx.y * 64;
    const int klo = blockIdx.x * 64;       // 0..511 range
    const int khi = klo + 512;
    const int tx = threadIdx.x & 63;
    const int ty = threadIdx.x >> 6;
#pragma unroll
    for (int u = 0; u < 64; u += 4) {
        const int t = t0 + u + ty;
        const long rb = (long)t * KK;
        const float xa = b2f(x[zoff + rb + klo + tx]);
        const float xb = b2f(x[zoff + rb + khi + tx]);
        const float ca = cosH[t * 512 + klo + tx];
        const float sa = sinH[t * 512 + klo + tx];
        const float qa = xa * ca - xb * sa;   // k <  512: rotate_half = -x[k+512]
        const float qb = xb * ca + xa * sa;   // k >= 512: rotate_half =  x[k-512] (cos/sin repeat)
        const u16 qab = f2b(qa), qbb = f2b(qb);
        q[zoff + rb + klo + tx] = qab;
        q[zoff + rb + khi + tx] = qbb;
        Sa[u + ty][tx] = qab;
        Sb[u + ty][tx] = qbb;
    }
    __syncthreads();
#pragma unroll
    for (int u = 0; u < 64; u += 4) {
        const int r = u + ty;
        qT[zoff + (long)(klo + r) * TT + t0 + tx] = Sa[tx][r];
        qT[zoff + (long)(khi + r) * TT + t0 + tx] = Sb[tx][r];
    }
}

// ---------------- bf16 MFMA GEMM, m97 structure ----------------
// C[m,n] = epi( sum_k A[m,k] * Bt[n,k] )   A:[M,Kin] bf16, Bt:[N,Kin] bf16
// 128x128 tile, BK=64, 4 waves (2x2), each wave 64x64 via 4x4 frags of 16x16x32.
// Staging: global_load_lds width-16, LINEAR LDS [128][64] (rule #21: linear dest
// + linear read; swizzle omitted — pays only at 8-phase, m252).
// EPI: 0=none 1=relu 2=relu*G.  batch z: zo=z/HH, zi=z%HH strides.
template <int EPI, typename TC>
__global__ __launch_bounds__(256)
void gemm_mfma(const u16* __restrict__ Ab, const u16* __restrict__ Btb,
               TC* __restrict__ Cb, const u16* __restrict__ Gb,
               int M, int N, int Kin, int lda, int ldb, int ldc, int ldg,
               long sAo, long sAi, long sBo, long sBi,
               long sCo, long sCi, long sGo, long sGi, int HH)
{
    const int z = blockIdx.z;
    const int zo = z / HH, zi = z - zo * HH;
    const u16* A  = Ab  + zo * sAo + zi * sAi;
    const u16* Bt = Btb + zo * sBo + zi * sBi;
    TC* C = Cb + zo * sCo + zi * sCi;
    const u16* G = (EPI == 2) ? (Gb + zo * sGo + zi * sGi) : nullptr;

    const int m0 = blockIdx.y * 128;
    const int n0 = blockIdx.x * 128;
    const int tid = threadIdx.x;
    const int lane = tid & 63;
    const int wv = tid >> 6;
    const int wr = (wv >> 1) * 64;
    const int wc = (wv & 1) * 64;

    __shared__ u16 As[128 * 64];
    __shared__ u16 Bs[128 * 64];

    f32x4 acc[4][4];
    const f32x4 vzero = {0.f, 0.f, 0.f, 0.f};
#pragma unroll
    for (int i = 0; i < 4; ++i)
#pragma unroll
        for (int j = 0; j < 4; ++j) acc[i][j] = vzero;

    // staging geometry: unit u = it*256+tid (16B units); row = u>>3, slot = u&7
    const int rbase = tid >> 3;           // 0..31
    const int slot  = tid & 7;
    const u16* Abase = A  + (long)(m0 + rbase) * lda + slot * 8;
    const u16* Bbase = Bt + (long)(n0 + rbase) * ldb + slot * 8;
    const int ldsU = (tid & 192) * 8;     // wave-uniform u16 base within a 256-unit group

    const int rl = lane & 15;
    const int kg = lane >> 4;

    for (int k0 = 0; k0 < Kin; k0 += 64) {
#pragma unroll
        for (int it = 0; it < 4; ++it) {
            __builtin_amdgcn_global_load_lds(
                (const __attribute__((address_space(1))) unsigned int*)(Abase + (long)it * 32 * lda + k0),
                (__attribute__((address_space(3))) unsigned int*)(As + it * 2048 + ldsU),
                16, 0, 0);
            __builtin_amdgcn_global_load_lds(
                (const __attribute__((address_space(1))) unsigned int*)(Bbase + (long)it * 32 * ldb + k0),
                (__attribute__((address_space(3))) unsigned int*)(Bs + it * 2048 + ldsU),
                16, 0, 0);
        }
        __syncthreads();   // compiler drains vmcnt(0) before barrier
#pragma unroll
        for (int kk = 0; kk < 2; ++kk) {
            const int sl = kk * 4 + kg;
            short8 af[4], bfr[4];
#pragma unroll
            for (int i = 0; i < 4; ++i)
                af[i] = *(const short8*)(&As[(wr + i * 16 + rl) * 64 + sl * 8]);
#pragma unroll
            for (int j = 0; j < 4; ++j)
                bfr[j] = *(const short8*)(&Bs[(wc + j * 16 + rl) * 64 + sl * 8]);
#pragma unroll
            for (int i = 0; i < 4; ++i)
#pragma unroll
                for (int j = 0; j < 4; ++j)
                    acc[i][j] = __builtin_amdgcn_mfma_f32_16x16x32_bf16(af[i], bfr[j], acc[i][j], 0, 0, 0);
        }
        __syncthreads();
    }

    // C/D layout: col = lane&15, row = (lane>>4)*4 + reg  [m89-verified]
#pragma unroll
    for (int i = 0; i < 4; ++i) {
#pragma unroll
        for (int rr = 0; rr < 4; ++rr) {
            const int m = m0 + wr + i * 16 + kg * 4 + rr;
#pragma unroll
            for (int j = 0; j < 4; ++j) {
                const int n = n0 + wc + j * 16 + rl;
                float val = acc[i][j][rr];
                if (EPI >= 1) val = fmaxf(val, 0.f);
                if (EPI == 2) val *= b2f(G[(long)m * ldg + n]);
                stF(&C[(long)m * ldc + n], val);
            }
        }
    }
}

extern "C" void kernel_launch(void* const* d_in, const int* in_sizes, int n_in,
                              void* d_out, int out_size, void* d_ws, size_t ws_size,
                              hipStream_t stream)
{
    const int* input_ = (const int*)d_in[0];
    const float* emb = (const float*)d_in[1];
    const float* pos = (const float*)d_in[2];
    const float* Dx = (const float*)d_in[3];
    const float* Dy = (const float*)d_in[4];
    const float* E  = (const float*)d_in[5];
    const float* readout = (const float*)d_in[6];
    float* out = (float*)d_out;

    // -------- workspace layout (byte offsets); total ~162 MiB --------
    char* base = (char*)d_ws;
    const long MiB = 1024 * 1024;
    float* v     = (float*)(base + 0);         //  4 MiB fp32 residual (incl. pos)
    float* zpart = (float*)(base + 4  * MiB);  // 16 MiB fp32, 4 split-K slices of y@E
    float* cosH  = (float*)(base + 20 * MiB);  //  4 MiB [T][512]
    float* sinH  = (float*)(base + 24 * MiB);  //  4 MiB
    u16* vbf  = (u16*)(base + 28 * MiB);       //  2 MiB bf16 [B][T][D]
    u16* vbfT = (u16*)(base + 30 * MiB);       //  2 MiB bf16 [B][D][T]
    u16* wT   = (u16*)(base + 32 * MiB);       //  4 MiB bf16 [B][H][D][K]
    u16* x    = (u16*)(base + 36 * MiB);       // 32 MiB bf16 [B][H][T][K]
    u16* q    = (u16*)(base + 68 * MiB);       // 32 MiB bf16 [B][H][T][K]
    u16* y    = q;                             // alias: q dead after a-gemm
    u16* qT   = (u16*)(base + 100 * MiB);      // 32 MiB bf16 [B][H][K][T]
    float* a  = (float*)qT;                    // 16 MiB alias: qT dead after wT-gemm
    u16* lnab = (u16*)(base + 132 * MiB);      //  8 MiB bf16 [B][H][T][D]
    u16* DxT  = (u16*)(base + 140 * MiB);      //  2 MiB bf16 [H][K][D]
    u16* DyT  = (u16*)(base + 142 * MiB);      //  2 MiB bf16 [H][K][D]
    u16* ET   = (u16*)(base + 144 * MiB);      //  2 MiB bf16 [D][NN]
    u16* roT  = (u16*)(base + 146 * MiB);      // 15.63 MiB bf16 [V][D]

    // -------- constants: transpose+convert once per call --------
    k_trans<float><<<dim3(KK / 32, DD / 32, HH_), 256, 0, stream>>>(Dx, DxT, DD, KK);
    k_trans<float><<<dim3(KK / 32, DD / 32, HH_), 256, 0, stream>>>(Dy, DyT, DD, KK);
    k_trans<float><<<dim3(DD / 32, NN / 32, 1),   256, 0, stream>>>(E, ET, NN, DD);
    k_trans<float><<<dim3(VV / 32, DD / 32, 1),   256, 0, stream>>>(readout, roT, DD, VV);
    k_sincos<<<TT, 256, 0, stream>>>(cosH, sinH);
    k_embed_ln<<<BT, 256, 0, stream>>>(input_, emb, pos, v, vbf);

    for (int l = 0; l < LL; ++l) {
        k_trans<u16><<<dim3(DD / 32, TT / 32, BB), 256, 0, stream>>>(vbf, vbfT, TT, DD);

        // x[b,h] = relu(v[b] @ Dx[h]) : M=T, N=K, Kin=D
        gemm_mfma<1, u16><<<dim3(KK / 128, TT / 128, BB * HH_), 256, 0, stream>>>(
            vbf, DxT, x, nullptr,
            TT, KK, DD, DD, DD, KK, 0,
            (long)TT * DD, 0, 0, (long)KK * DD,
            (long)HH_ * TT * KK, (long)TT * KK, 0, 0, HH_);

        k_rope_t<<<dim3(8, TT / 64, BB * HH_), 256, 0, stream>>>(x, cosH, sinH, q, qT);

        // wT[b,h] = v[b]^T @ q[b,h]  (scores associativity) : M=D, N=K, Kin=T
        gemm_mfma<0, u16><<<dim3(KK / 128, DD / 128, BB * HH_), 256, 0, stream>>>(
            vbfT, qT, wT, nullptr,
            DD, KK, TT, TT, TT, KK, 0,
            (long)DD * TT, 0, (long)HH_ * KK * TT, (long)KK * TT,
            (long)HH_ * DD * KK, (long)DD * KK, 0, 0, HH_);

        // a[b,h] = q[b,h] @ w[b,h] : M=T, N=D, Kin=K  (fp32 out for LN)
        gemm_mfma<0, float><<<dim3(DD / 128, TT / 128, BB * HH_), 256, 0, stream>>>(
            q, wT, a, nullptr,
            TT, DD, KK, KK, KK, DD, 0,
            (long)HH_ * TT * KK, (long)TT * KK, (long)HH_ * DD * KK, (long)DD * KK,
            (long)HH_ * TT * DD, (long)TT * DD, 0, 0, HH_);

        k_ln_rows_out<<<BB * HH_ * TT, 256, 0, stream>>>(a, lnab);

        // y[b,t,h*K+k] = relu(ln_a @ Dy[h]) * x : M=T, N=K, Kin=D (y aliases q)
        gemm_mfma<2, u16><<<dim3(KK / 128, TT / 128, BB * HH_), 256, 0, stream>>>(
            lnab, DyT, y, x,
            TT, KK, DD, DD, DD, NN, KK,
            (long)HH_ * TT * DD, (long)TT * DD, 0, (long)KK * DD,
            (long)TT * NN, (long)KK, (long)HH_ * TT * KK, (long)TT * KK, HH_);

        // zpart[s] = y[:, s*1024:(s+1)*1024] @ E[s*1024:(s+1)*1024, :]
        // split-K x4 via batch z: 64 -> 256 workgroups; fp32 partials summed in k_fin_ln
        gemm_mfma<0, float><<<dim3(DD / 128, BT / 128, 4), 256, 0, stream>>>(
            y, ET, zpart, nullptr,
            BT, DD, KK, NN, NN, DD, 0,
            1024, 0, 1024, 0,
            (long)BT * DD, 0, 0, 0, 1);

        k_fin_ln<<<BT, 256, 0, stream>>>(v, zpart, pos, vbf, (l < LL - 1) ? 1 : 0);
    }

    // out = v @ readout : M=BT, N=V, Kin=D (fp32 out)
    gemm_mfma<0, float><<<dim3(VV / 128, BT / 128, 1), 256, 0, stream>>>(
        vbf, roT, out, nullptr,
        BT, VV, DD, DD, DD, VV, 0,
        0, 0, 0, 0, 0, 0, 0, 0, 1);
}

// Round 3
// 1551.198 us; speedup vs baseline: 3.9997x; 1.1258x over previous
//
#include <hip/hip_runtime.h>
#include <hip/hip_bf16.h>

using u16 = unsigned short;

#define BB 2
#define TT 2048
#define DD 256
#define HH_ 4
#define KK 1024
#define NN 4096
#define VV 32000
#define BT 4096
#define LL 6

typedef __attribute__((ext_vector_type(8))) short short8;
typedef __attribute__((ext_vector_type(4))) short short4v;
typedef __attribute__((ext_vector_type(4))) float f32x4;

__device__ __forceinline__ float b2f(u16 u) {
    union { unsigned int i; float f; } cv; cv.i = ((unsigned int)u) << 16; return cv.f;
}
__device__ __forceinline__ u16 f2b(float f) {
    union { float f; unsigned int i; } cv; cv.f = f;
    const unsigned int u = cv.i;
    return (u16)((u + 0x7fffu + ((u >> 16) & 1u)) >> 16);   // RNE
}
__device__ __forceinline__ float rdF(const float* p) { return *p; }
__device__ __forceinline__ float rdF(const u16* p)   { return b2f(*p); }
__device__ __forceinline__ void stF(float* p, float v) { *p = v; }
__device__ __forceinline__ void stF(u16* p, float v)   { *p = f2b(v); }

// ---------------- block-wide sum over 256 threads (4 waves) ----------------
__device__ __forceinline__ float block_sum_256(float val, float* sbuf) {
#pragma unroll
    for (int off = 32; off > 0; off >>= 1)
        val += __shfl_down(val, off, 64);
    const int lane = threadIdx.x & 63;
    const int wid  = threadIdx.x >> 6;
    __syncthreads();
    if (lane == 0) sbuf[wid] = val;
    __syncthreads();
    return sbuf[0] + sbuf[1] + sbuf[2] + sbuf[3];
}

// ---------------- rope tables, halved: cos/sin[t][f], f<512 ----------------
__global__ void k_sincos(float* __restrict__ cosH, float* __restrict__ sinH) {
    const int t = blockIdx.x;
    for (int f = threadIdx.x; f < 512; f += blockDim.x) {
        const double invf = exp(-((double)(2 * f) / (double)KK) * 9.210340371976184); // ln(10000)
        const double th = (double)t * invf;
        double s, c;
        sincos(th, &s, &c);
        cosH[t * 512 + f] = (float)c;
        sinH[t * 512 + f] = (float)s;
    }
}

// ---------------- v = ln(emb[input_]) + pos ----------------
__global__ void k_embed_ln(const int* __restrict__ idx, const float* __restrict__ emb,
                           const float* __restrict__ pos,
                           float* __restrict__ v, u16* __restrict__ vbf) {
    __shared__ float sbuf[4];
    const int r = blockIdx.x;
    const int t = r & (TT - 1);
    const int token = idx[r];
    const float xv = emb[(long)token * DD + threadIdx.x];
    const float mu = block_sum_256(xv, sbuf) * (1.f / DD);
    const float d = xv - mu;
    const float var = block_sum_256(d * d, sbuf) * (1.f / DD);
    const float res = d / sqrtf(var + 1e-5f) + pos[t * DD + threadIdx.x];
    v[(long)r * DD + threadIdx.x] = res;
    vbf[(long)r * DD + threadIdx.x] = f2b(res);
}

// ---------------- ln rows of (apart[0]+apart[1]) -> lnab (bf16) ----------------
__global__ void k_ln_rows_out(const float* __restrict__ a, u16* __restrict__ o) {
    __shared__ float sbuf[4];
    const long r = blockIdx.x;
    const long S = (long)BB * HH_ * TT * DD;
    const long i = r * DD + threadIdx.x;
    const float xv = a[i] + a[i + S];
    const float mu = block_sum_256(xv, sbuf) * (1.f / DD);
    const float d = xv - mu;
    const float var = block_sum_256(d * d, sbuf) * (1.f / DD);
    o[i] = f2b(d / sqrtf(var + 1e-5f));
}

// ---------------- v = ln(v + ln(sum_8 zp)) (+pos); emit vbf ----------------
__global__ void k_fin_ln(float* __restrict__ v, const float* __restrict__ zp,
                         const float* __restrict__ pos, u16* __restrict__ vbf,
                         int addp) {
    __shared__ float sbuf[4];
    const long r = blockIdx.x;
    const int t = (int)(r & (TT - 1));
    const long i = r * DD + threadIdx.x;
    const long S = (long)BT * DD;
    float zv = 0.f;
#pragma unroll
    for (int s = 0; s < 8; ++s) zv += zp[i + s * S];
    const float mu1 = block_sum_256(zv, sbuf) * (1.f / DD);
    const float d1 = zv - mu1;
    const float var1 = block_sum_256(d1 * d1, sbuf) * (1.f / DD);
    const float lnz = d1 / sqrtf(var1 + 1e-5f);
    const float u = v[i] + lnz;
    const float mu2 = block_sum_256(u, sbuf) * (1.f / DD);
    const float d2 = u - mu2;
    const float var2 = block_sum_256(d2 * d2, sbuf) * (1.f / DD);
    float res = d2 / sqrtf(var2 + 1e-5f);
    if (addp) res += pos[t * DD + threadIdx.x];
    v[i] = res;
    vbf[i] = f2b(res);
}

// ---------------- wT = bf16( sum_4 wpart slices ) ----------------
__global__ void k_red_wT(const float* __restrict__ wp, u16* __restrict__ o) {
    const long S = (long)BB * HH_ * DD * KK;   // 2,097,152
    const long i0 = ((long)blockIdx.x * 256 + threadIdx.x) * 4;
    f32x4 a = *(const f32x4*)(wp + i0);
    f32x4 b = *(const f32x4*)(wp + i0 + S);
    f32x4 c = *(const f32x4*)(wp + i0 + 2 * S);
    f32x4 d = *(const f32x4*)(wp + i0 + 3 * S);
    short4v r;
#pragma unroll
    for (int j = 0; j < 4; ++j) r[j] = (short)f2b(a[j] + b[j] + c[j] + d[j]);
    *(short4v*)(o + i0) = r;
}

// ---------------- transpose+convert: in [z][R][C] -> out bf16 [z][C][R] ----------------
template <typename TIN>
__global__ __launch_bounds__(256)
void k_trans(const TIN* __restrict__ in, u16* __restrict__ out, int R, int C) {
    __shared__ float tile[32][33];
    const long zo = (long)blockIdx.z * (long)R * (long)C;
    const int r0 = blockIdx.y * 32, c0 = blockIdx.x * 32;
    const int tx = threadIdx.x & 31, ty = threadIdx.x >> 5;
#pragma unroll
    for (int u = 0; u < 32; u += 8)
        tile[ty + u][tx] = rdF(&in[zo + (long)(r0 + ty + u) * C + c0 + tx]);
    __syncthreads();
#pragma unroll
    for (int u = 0; u < 32; u += 8)
        out[zo + (long)(c0 + ty + u) * R + r0 + tx] = f2b(tile[tx][ty + u]);
}

// ---------------- rope: x(bf16) -> q(bf16) and qT(bf16); halved tables ----------------
__global__ __launch_bounds__(256)
void k_rope_t(const u16* __restrict__ x, const float* __restrict__ cosH,
              const float* __restrict__ sinH, u16* __restrict__ q, u16* __restrict__ qT) {
    __shared__ u16 Sa[64][72];
    __shared__ u16 Sb[64][72];
    const long zoff = (long)blockIdx.z * TT * KK;
    const int t0 = blockIdx.y * 64;
    const int klo = blockIdx.x * 64;       // 0..511
    const int khi = klo + 512;
    const int tx = threadIdx.x & 63;
    const int ty = threadIdx.x >> 6;
#pragma unroll
    for (int u = 0; u < 64; u += 4) {
        const int t = t0 + u + ty;
        const long rb = (long)t * KK;
        const float xa = b2f(x[zoff + rb + klo + tx]);
        const float xb = b2f(x[zoff + rb + khi + tx]);
        const float ca = cosH[t * 512 + klo + tx];
        const float sa = sinH[t * 512 + klo + tx];
        const float qa = xa * ca - xb * sa;
        const float qb = xb * ca + xa * sa;
        const u16 qab = f2b(qa), qbb = f2b(qb);
        q[zoff + rb + klo + tx] = qab;
        q[zoff + rb + khi + tx] = qbb;
        Sa[u + ty][tx] = qab;
        Sb[u + ty][tx] = qbb;
    }
    __syncthreads();
#pragma unroll
    for (int u = 0; u < 64; u += 4) {
        const int r = u + ty;
        qT[zoff + (long)(klo + r) * TT + t0 + tx] = Sa[tx][r];
        qT[zoff + (long)(khi + r) * TT + t0 + tx] = Sb[tx][r];
    }
}

// ---------------- bf16 MFMA GEMM, m97 structure, BM x 128 tile ----------------
// C[m,n] = epi( sum_k A[m,k] * Bt[n,k] ),  BM in {128,256}, THREADS = BM*2.
// Waves (BM/64 x 2), each 64x64 via 4x4 frags of 16x16x32, BK=64.
// Staging: global_load_lds width-16 into LINEAR LDS.
// Split-K: s = z/ZB picks slice; A += s*sAk, Bt += s*sBk, C += s*sCk.
// EPI: 0=none 1=relu 2=relu*G.
template <int BM, int EPI, typename TC>
__global__ __launch_bounds__(BM * 2)
void gemm_mfma(const u16* __restrict__ Ab, const u16* __restrict__ Btb,
               TC* __restrict__ Cb, const u16* __restrict__ Gb,
               int M, int N, int Kin, int lda, int ldb, int ldc, int ldg,
               long sAo, long sAi, long sBo, long sBi,
               long sCo, long sCi, long sGo, long sGi,
               int HH, int ZB, long sAk, long sBk, long sCk)
{
    constexpr int THREADS = BM * 2;
    constexpr int RPI = THREADS / 8;        // rows staged per iteration
    constexpr int B_ITS = 1024 / THREADS;   // B: 128 rows * 8 slots / THREADS
    int z = blockIdx.z;
    const int s = z / ZB; z -= s * ZB;
    const int zo = z / HH, zi = z - zo * HH;
    const u16* A  = Ab  + zo * sAo + zi * sAi + (long)s * sAk;
    const u16* Bt = Btb + zo * sBo + zi * sBi + (long)s * sBk;
    TC* C = Cb + zo * sCo + zi * sCi + (long)s * sCk;
    const u16* G = (EPI == 2) ? (Gb + zo * sGo + zi * sGi) : nullptr;

    const int m0 = blockIdx.y * BM;
    const int n0 = blockIdx.x * 128;
    const int tid = threadIdx.x;
    const int lane = tid & 63;
    const int wv = tid >> 6;
    const int wr = (wv >> 1) * 64;
    const int wc = (wv & 1) * 64;

    __shared__ u16 As[BM * 64];
    __shared__ u16 Bs[128 * 64];

    f32x4 acc[4][4];
    const f32x4 vzero = {0.f, 0.f, 0.f, 0.f};
#pragma unroll
    for (int i = 0; i < 4; ++i)
#pragma unroll
        for (int j = 0; j < 4; ++j) acc[i][j] = vzero;

    const int rbase = tid >> 3;             // 0..RPI-1
    const int slot  = tid & 7;
    const u16* Abase = A  + (long)(m0 + rbase) * lda + slot * 8;
    const u16* Bbase = Bt + (long)(n0 + rbase) * ldb + slot * 8;
    const int wub = (tid & ~63) * 8;        // wave-uniform u16 base within a THREADS-unit group

    const int rl = lane & 15;
    const int kg = lane >> 4;

    for (int k0 = 0; k0 < Kin; k0 += 64) {
#pragma unroll
        for (int it = 0; it < 4; ++it) {
            __builtin_amdgcn_global_load_lds(
                (const __attribute__((address_space(1))) unsigned int*)(Abase + (long)it * RPI * lda + k0),
                (__attribute__((address_space(3))) unsigned int*)(As + it * (THREADS * 8) + wub),
                16, 0, 0);
        }
#pragma unroll
        for (int it = 0; it < B_ITS; ++it) {
            __builtin_amdgcn_global_load_lds(
                (const __attribute__((address_space(1))) unsigned int*)(Bbase + (long)it * RPI * ldb + k0),
                (__attribute__((address_space(3))) unsigned int*)(Bs + it * (THREADS * 8) + wub),
                16, 0, 0);
        }
        __syncthreads();
#pragma unroll
        for (int kk = 0; kk < 2; ++kk) {
            const int sl = kk * 4 + kg;
            short8 af[4], bfr[4];
#pragma unroll
            for (int i = 0; i < 4; ++i)
                af[i] = *(const short8*)(&As[(wr + i * 16 + rl) * 64 + sl * 8]);
#pragma unroll
            for (int j = 0; j < 4; ++j)
                bfr[j] = *(const short8*)(&Bs[(wc + j * 16 + rl) * 64 + sl * 8]);
#pragma unroll
            for (int i = 0; i < 4; ++i)
#pragma unroll
                for (int j = 0; j < 4; ++j)
                    acc[i][j] = __builtin_amdgcn_mfma_f32_16x16x32_bf16(af[i], bfr[j], acc[i][j], 0, 0, 0);
        }
        __syncthreads();
    }

    // C/D layout: col = lane&15, row = (lane>>4)*4 + reg
#pragma unroll
    for (int i = 0; i < 4; ++i) {
#pragma unroll
        for (int rr = 0; rr < 4; ++rr) {
            const int m = m0 + wr + i * 16 + kg * 4 + rr;
#pragma unroll
            for (int j = 0; j < 4; ++j) {
                const int n = n0 + wc + j * 16 + rl;
                float val = acc[i][j][rr];
                if (EPI >= 1) val = fmaxf(val, 0.f);
                if (EPI == 2) val *= b2f(G[(long)m * ldg + n]);
                stF(&C[(long)m * ldc + n], val);
            }
        }
    }
}

extern "C" void kernel_launch(void* const* d_in, const int* in_sizes, int n_in,
                              void* d_out, int out_size, void* d_ws, size_t ws_size,
                              hipStream_t stream)
{
    const int* input_ = (const int*)d_in[0];
    const float* emb = (const float*)d_in[1];
    const float* pos = (const float*)d_in[2];
    const float* Dx = (const float*)d_in[3];
    const float* Dy = (const float*)d_in[4];
    const float* E  = (const float*)d_in[5];
    const float* readout = (const float*)d_in[6];
    float* out = (float*)d_out;

    // -------- workspace layout (byte offsets); total ~210 MiB --------
    char* base = (char*)d_ws;
    const long MiB = 1024 * 1024;
    float* v     = (float*)(base + 0);         //   4 MiB fp32 residual
    float* zpart = (float*)(base + 4  * MiB);  //  32 MiB fp32, 8 split-K slices of y@E
    float* cosH  = (float*)(base + 36 * MiB);  //   4 MiB [T][512]
    float* sinH  = (float*)(base + 40 * MiB);  //   4 MiB
    u16* vbf   = (u16*)(base + 44 * MiB);      //   2 MiB bf16 [B][T][D]
    u16* vbfT  = (u16*)(base + 46 * MiB);      //   2 MiB bf16 [B][D][T]
    u16* wTb   = (u16*)(base + 48 * MiB);      //   4 MiB bf16 [B][H][D][K]
    float* wpart = (float*)(base + 52 * MiB);  //  32 MiB fp32: 4 slices wT partials
    float* apart = wpart;                      //  32 MiB alias: 2 slices a partials (wpart dead)
    u16* x     = (u16*)(base + 84 * MiB);      //  32 MiB bf16 [B][H][T][K]
    u16* q     = (u16*)(base + 116 * MiB);     //  32 MiB bf16 [B][H][T][K]
    u16* y     = q;                            //  alias: q dead after a-gemm
    u16* qT    = (u16*)(base + 148 * MiB);     //  32 MiB bf16 [B][H][K][T]
    u16* lnab  = (u16*)(base + 180 * MiB);     //   8 MiB bf16 [B][H][T][D]
    u16* DxT   = (u16*)(base + 188 * MiB);     //   2 MiB bf16 [H][K][D]
    u16* DyT   = (u16*)(base + 190 * MiB);     //   2 MiB bf16 [H][K][D]
    u16* ET    = (u16*)(base + 192 * MiB);     //   2 MiB bf16 [D][NN]
    u16* roT   = (u16*)(base + 194 * MiB);     // 15.63 MiB bf16 [V][D]

    // -------- constants --------
    k_trans<float><<<dim3(KK / 32, DD / 32, HH_), 256, 0, stream>>>(Dx, DxT, DD, KK);
    k_trans<float><<<dim3(KK / 32, DD / 32, HH_), 256, 0, stream>>>(Dy, DyT, DD, KK);
    k_trans<float><<<dim3(DD / 32, NN / 32, 1),   256, 0, stream>>>(E, ET, NN, DD);
    k_trans<float><<<dim3(VV / 32, DD / 32, 1),   256, 0, stream>>>(readout, roT, DD, VV);
    k_sincos<<<TT, 256, 0, stream>>>(cosH, sinH);
    k_embed_ln<<<BT, 256, 0, stream>>>(input_, emb, pos, v, vbf);

    for (int l = 0; l < LL; ++l) {
        k_trans<u16><<<dim3(DD / 32, TT / 32, BB), 256, 0, stream>>>(vbf, vbfT, TT, DD);

        // x[b,h] = relu(v[b] @ Dx[h]) : M=T, N=K, Kin=D ; BM=256 -> 8x8x8=512 wg
        gemm_mfma<256, 1, u16><<<dim3(KK / 128, TT / 256, BB * HH_), 512, 0, stream>>>(
            vbf, DxT, x, nullptr,
            TT, KK, DD, DD, DD, KK, 0,
            (long)TT * DD, 0, 0, (long)KK * DD,
            (long)HH_ * TT * KK, (long)TT * KK, 0, 0,
            HH_, BB * HH_, 0, 0, 0);

        k_rope_t<<<dim3(8, TT / 64, BB * HH_), 256, 0, stream>>>(x, cosH, sinH, q, qT);

        // wpart[s][b,h] = vT[b][:, s*512:] @ q-slice : M=D, N=K, Kin=512, split-K x4 -> 512 wg
        gemm_mfma<128, 0, float><<<dim3(KK / 128, DD / 128, 4 * BB * HH_), 256, 0, stream>>>(
            vbfT, qT, wpart, nullptr,
            DD, KK, TT / 4, TT, TT, KK, 0,
            (long)DD * TT, 0, (long)HH_ * KK * TT, (long)KK * TT,
            (long)HH_ * DD * KK, (long)DD * KK, 0, 0,
            HH_, BB * HH_, 512, 512, (long)BB * HH_ * DD * KK);

        k_red_wT<<<2048, 256, 0, stream>>>(wpart, wTb);

        // apart[s][b,h] = q-slice @ w-slice : M=T, N=D, Kin=512, split-K x2 -> 512 wg
        gemm_mfma<128, 0, float><<<dim3(DD / 128, TT / 128, 2 * BB * HH_), 256, 0, stream>>>(
            q, wTb, apart, nullptr,
            TT, DD, KK / 2, KK, KK, DD, 0,
            (long)HH_ * TT * KK, (long)TT * KK, (long)HH_ * DD * KK, (long)DD * KK,
            (long)HH_ * TT * DD, (long)TT * DD, 0, 0,
            HH_, BB * HH_, 512, 512, (long)BB * HH_ * TT * DD);

        k_ln_rows_out<<<BB * HH_ * TT, 256, 0, stream>>>(apart, lnab);

        // y = relu(ln_a @ Dy) * x : M=T, N=K, Kin=D ; BM=256 -> 512 wg (y aliases q)
        gemm_mfma<256, 2, u16><<<dim3(KK / 128, TT / 256, BB * HH_), 512, 0, stream>>>(
            lnab, DyT, y, x,
            TT, KK, DD, DD, DD, NN, KK,
            (long)HH_ * TT * DD, (long)TT * DD, 0, (long)KK * DD,
            (long)TT * NN, (long)KK, (long)HH_ * TT * KK, (long)TT * KK,
            HH_, BB * HH_, 0, 0, 0);

        // zpart[s] = y-slice @ E-slice : M=BT, N=D, Kin=512, split-K x8 -> 512 wg
        gemm_mfma<128, 0, float><<<dim3(DD / 128, BT / 128, 8), 256, 0, stream>>>(
            y, ET, zpart, nullptr,
            BT, DD, NN / 8, NN, NN, DD, 0,
            0, 0, 0, 0, 0, 0, 0, 0,
            1, 1, 512, 512, (long)BT * DD);

        k_fin_ln<<<BT, 256, 0, stream>>>(v, zpart, pos, vbf, (l < LL - 1) ? 1 : 0);
    }

    // out = v @ readout : M=BT, N=V, Kin=D ; BM=256 -> 250x16=4000 wg
    gemm_mfma<256, 0, float><<<dim3(VV / 128, BT / 256, 1), 512, 0, stream>>>(
        vbf, roT, out, nullptr,
        BT, VV, DD, DD, DD, VV, 0,
        0, 0, 0, 0, 0, 0, 0, 0,
        1, 1, 0, 0, 0);
}